// Round 5
// baseline (1561.786 us; speedup 1.0000x reference)
//
#include <hip/hip_runtime.h>

typedef short bf16x8 __attribute__((ext_vector_type(8)));
typedef float f32x4  __attribute__((ext_vector_type(4)));

#define TSTEPS 1000
#define BATCH  512
#define HID    64
#define INPD   64
#define FEAT   128
#define KEEP   5
#define KH     320
#define ALPHA  0.2f
#define BB     2
#define NBLK   (BATCH/BB)   // 256
#define NTHR   512

#define MFMA(a,b,c) __builtin_amdgcn_mfma_f32_16x16x32_bf16(a, b, c, 0, 0, 0)

template<int P> struct IC { static constexpr int v = P; };

// split 4 f32 into bf16-hi (truncated) and bf16-lo (rounded residual), packed 2-per-u32
__device__ __forceinline__ void pack4(float x0, float x1, float x2, float x3,
                                      unsigned &h0, unsigned &h1,
                                      unsigned &l0, unsigned &l1) {
  unsigned a0 = __float_as_uint(x0), a1 = __float_as_uint(x1);
  unsigned a2 = __float_as_uint(x2), a3 = __float_as_uint(x3);
  h0 = __builtin_amdgcn_perm(a1, a0, 0x07060302u);   // {bf16(x1), bf16(x0)}
  h1 = __builtin_amdgcn_perm(a3, a2, 0x07060302u);
  float r0 = x0 - __uint_as_float(a0 & 0xFFFF0000u);
  float r1 = x1 - __uint_as_float(a1 & 0xFFFF0000u);
  float r2 = x2 - __uint_as_float(a2 & 0xFFFF0000u);
  float r3 = x3 - __uint_as_float(a3 & 0xFFFF0000u);
  asm("v_cvt_pk_bf16_f32 %0, %1, %2" : "=v"(l0) : "v"(r0), "v"(r1));
  asm("v_cvt_pk_bf16_f32 %0, %1, %2" : "=v"(l1) : "v"(r2), "v"(r3));
}

__device__ __forceinline__ void pack_frag(float4 v0, float4 v1, bf16x8 &hi, bf16x8 &lo) {
  int4 h4, l4;
  pack4(v0.x, v0.y, v0.z, v0.w, (unsigned&)h4.x, (unsigned&)h4.y, (unsigned&)l4.x, (unsigned&)l4.y);
  pack4(v1.x, v1.y, v1.z, v1.w, (unsigned&)h4.z, (unsigned&)h4.w, (unsigned&)l4.z, (unsigned&)l4.w);
  hi = __builtin_bit_cast(bf16x8, h4);
  lo = __builtin_bit_cast(bf16x8, l4);
}

__device__ __forceinline__ void load_wfrag(const float* p, bf16x8 &hi, bf16x8 &lo) {
  float4 v0 = *(const float4*)p;
  float4 v1 = *(const float4*)(p + 4);
  pack_frag(v0, v1, hi, lo);
}

// ---------------- single persistent MFMA kernel ----------------
// 256 blocks (1/CU) x 8 waves, BB=2. Two barriers per step.
// P1 (18 MFMA/wave): w0-3: XIN(x_t)+RNN(h_{t-1})+newest-slot MLP1 -> hobs, a_s
//                    w4-7: MLP1 ranks 2,3 + newest -> a_s
// P2 (24 MFMA/wave): w0-3: MLP1(t+1) ranks 0-3 (carried acc) + pack x_{t+1}
//                    w4-7: MLP2 + MLP1(t+1) ranks 0,1 + finalize h_t, stage
__global__ __launch_bounds__(NTHR, 2) void seq_kernel(
    const float* __restrict__ x,    float* __restrict__ io,
    const float* __restrict__ h0g,
    const float* __restrict__ W_in, const float* __restrict__ b_in,
    const float* __restrict__ W_hh, const float* __restrict__ b_hh,
    const float* __restrict__ W1,   const float* __restrict__ b1,
    const float* __restrict__ W2,   const float* __restrict__ b2) {

  __shared__ __align__(16) short B1lds[2048];   // h_t frag staging [(q*2+sp)][g][col16][e8]
  __shared__ __align__(16) short a_s[544];      // relu(mlp1) bf16 [col2][sp2][f128], col stride 264
  __shared__ __align__(16) float hobs_s[128];   // [col2][h64]
  __shared__ __align__(16) float h_s[128];      // h_{t-1} f32 [col2][h64]

  const int tid  = threadIdx.x;
  const int w    = tid >> 6;
  const int lane = tid & 63;
  const int q15  = lane & 15;
  const int g    = lane >> 4;
  const int b0   = blockIdx.x * BB;
  const bool gA  = (w < 4);
  const int r0c  = 16*(w & 3) + 4*g;   // 64-row base (RNN / MLP2 / h)
  const int f0   = 16*w + 4*g;         // 128-row base (MLP1)
  const int c01  = q15 & 1;

  const int aW  = q15*264 + f0;        // a_s write (hi), +128 for lo; q15<2 only
  const int aRb = c01*264 + 8*g;       // a_s read base (+sp*128 +kt*32)
  const int bWH = (r0c>>5)*1024 + ((r0c>>3)&3)*128 + q15*8 + (r0c&7);
  const int bRD = g*128 + q15*8;

  const f32x4 vz = {0.f, 0.f, 0.f, 0.f};

  // ---- weight fragments ----
  bf16x8 w1h[10], w1l[10];
#pragma unroll
  for (int jt = 0; jt < 10; ++jt)
    load_wfrag(W1 + (size_t)(16*w + q15)*KH + jt*32 + 8*g, w1h[jt], w1l[jt]);

  bf16x8 wxh[4], wxl[4];   // w0-3: [0,1]=W_hh, [2,3]=W_in ; w4-7: [0..3]=W2
  f32x4 biasv = vz, b2r = vz;
  f32x4 b1r = *(const f32x4*)(b1 + f0);
  if (gA) {
#pragma unroll
    for (int kt = 0; kt < 2; ++kt) {
      load_wfrag(W_hh + (size_t)(16*w + q15)*HID  + kt*32 + 8*g, wxh[kt],   wxl[kt]);
      load_wfrag(W_in + (size_t)(16*w + q15)*INPD + kt*32 + 8*g, wxh[2+kt], wxl[2+kt]);
    }
    biasv = *(const f32x4*)(b_in + r0c) + *(const f32x4*)(b_hh + r0c);
  } else {
#pragma unroll
    for (int kt = 0; kt < 4; ++kt)
      load_wfrag(W2 + (size_t)(16*(w-4) + q15)*FEAT + kt*32 + 8*g, wxh[kt], wxl[kt]);
    b2r = *(const f32x4*)(b2 + r0c);
  }

  // ---- state init ----
  for (int i = tid; i < 1024; i += NTHR) ((unsigned*)B1lds)[i] = 0u;
  if (tid < 128) h_s[(tid & 1)*64 + (tid >> 1)] = h0g[(size_t)(b0 + (tid & 1))*HID + (tid >> 1)];
  __syncthreads();

  if (gA && q15 < 2) {   // stage h0 as the initial "newest" fragment
    f32x4 hv = *(const f32x4*)(h0g + (size_t)(b0 + q15)*HID + r0c);
    unsigned n0, n1, n2, n3;
    pack4(hv.x, hv.y, hv.z, hv.w, n0, n1, n2, n3);
    *(uint2*)&B1lds[bWH]       = make_uint2(n0, n1);
    *(uint2*)&B1lds[bWH + 512] = make_uint2(n2, n3);
  }

  // hidden ring fragments in registers
  bf16x8 rbh[KEEP][2], rbl[KEEP][2];
  const bf16x8 z8 = {0,0,0,0,0,0,0,0};
#pragma unroll
  for (int s = 0; s < KEEP; ++s) {
    rbh[s][0] = z8; rbl[s][0] = z8; rbh[s][1] = z8; rbl[s][1] = z8;
  }

  // x fragments: current (t) packed, next raw->packed pipeline
  bf16x8 xch[2], xcl[2];
  xch[0] = z8; xcl[0] = z8; xch[1] = z8; xcl[1] = z8;
  if (gA) {
    const float* xp = x + (size_t)(b0 + c01)*INPD + 8*g;
    load_wfrag(xp,      xch[0], xcl[0]);
    load_wfrag(xp + 32, xch[1], xcl[1]);
  }

  // carried MLP1 accumulators (zero: ring is zero for t=0's old slots)
  f32x4 chh = vz, chl = vz, clh = vz;
  __syncthreads();

  int t5 = 0;
  auto step = [&](auto pc) {
    constexpr int ph = decltype(pc)::v;
    constexpr int sN = (ph + 4) % 5;           // slot of h_{t-1}
    const int t = t5 + ph;

    // ---- P1 ----
    // issue x[t+1] raw loads (packed in P2, consumed next P1)
    float4 xr0, xr1, xr2, xr3;
    if (gA) {
      const int tn = (t + 1 < TSTEPS) ? t + 1 : t;
      const float* xp = x + (size_t)tn*BATCH*INPD + (size_t)(b0 + c01)*INPD + 8*g;
      xr0 = *(const float4*)xp;        xr1 = *(const float4*)(xp + 4);
      xr2 = *(const float4*)(xp + 32); xr3 = *(const float4*)(xp + 36);
    }

    // read newest h fragment + h_{t-1} f32
    bf16x8 nh0 = *(const bf16x8*)&B1lds[bRD];
    bf16x8 nl0 = *(const bf16x8*)&B1lds[bRD + 512];
    bf16x8 nh1 = *(const bf16x8*)&B1lds[bRD + 1024];
    bf16x8 nl1 = *(const bf16x8*)&B1lds[bRD + 1536];
    rbh[sN][0] = nh0; rbl[sN][0] = nl0; rbh[sN][1] = nh1; rbl[sN][1] = nl1;

    if (gA) {
      f32x4 hprev = *(const f32x4*)&h_s[c01*64 + r0c];
      // XIN (register operands, runs under LDS latency)
      f32x4 dhh = biasv, dhl = vz, dlh = vz;
      dhh = MFMA(wxh[2], xch[0], dhh); dhh = MFMA(wxh[3], xch[1], dhh);
      dhl = MFMA(wxh[2], xcl[0], dhl); dhl = MFMA(wxh[3], xcl[1], dhl);
      dlh = MFMA(wxl[2], xch[0], dlh); dlh = MFMA(wxl[3], xch[1], dlh);
      // RNN on newest frag
      dhh = MFMA(wxh[0], nh0, dhh); dhh = MFMA(wxh[1], nh1, dhh);
      dhl = MFMA(wxh[0], nl0, dhl); dhl = MFMA(wxh[1], nl1, dhl);
      dlh = MFMA(wxl[0], nh0, dlh); dlh = MFMA(wxl[1], nh1, dlh);
      // MLP1 newest slot (jt 8,9) into carried acc
      chh = MFMA(w1h[8], nh0, chh); chh = MFMA(w1h[9], nh1, chh);
      chl = MFMA(w1h[8], nl0, chl); chl = MFMA(w1h[9], nl1, chl);
      clh = MFMA(w1l[8], nh0, clh); clh = MFMA(w1l[9], nh1, clh);
      // finalize a, hobs
      f32x4 apre = (chh + chl) + (clh + b1r);
      f32x4 av = __builtin_elementwise_max(apre, vz);
      unsigned p0, p1, p2, p3;
      pack4(av.x, av.y, av.z, av.w, p0, p1, p2, p3);
      if (q15 < 2) {
        *(uint2*)&a_s[aW]       = make_uint2(p0, p1);
        *(uint2*)&a_s[aW + 128] = make_uint2(p2, p3);
      }
      f32x4 pre = (dhh + dhl) + dlh;
      f32x4 rl = __builtin_elementwise_max(pre, vz);
      f32x4 hobs = hprev * (1.f - ALPHA) + rl * ALPHA;
      if (q15 < 2) *(f32x4*)&hobs_s[q15*64 + r0c] = hobs;
    } else {
      // MLP1 ranks 2,3 (register ring) + newest
      chh = MFMA(w1h[4], rbh[(ph+2)%5][0], chh); chh = MFMA(w1h[5], rbh[(ph+2)%5][1], chh);
      chl = MFMA(w1h[4], rbl[(ph+2)%5][0], chl); chl = MFMA(w1h[5], rbl[(ph+2)%5][1], chl);
      clh = MFMA(w1l[4], rbh[(ph+2)%5][0], clh); clh = MFMA(w1l[5], rbh[(ph+2)%5][1], clh);
      chh = MFMA(w1h[6], rbh[(ph+3)%5][0], chh); chh = MFMA(w1h[7], rbh[(ph+3)%5][1], chh);
      chl = MFMA(w1h[6], rbl[(ph+3)%5][0], chl); chl = MFMA(w1h[7], rbl[(ph+3)%5][1], chl);
      clh = MFMA(w1l[6], rbh[(ph+3)%5][0], clh); clh = MFMA(w1l[7], rbh[(ph+3)%5][1], clh);
      chh = MFMA(w1h[8], nh0, chh); chh = MFMA(w1h[9], nh1, chh);
      chl = MFMA(w1h[8], nl0, chl); chl = MFMA(w1h[9], nl1, chl);
      clh = MFMA(w1l[8], nh0, clh); clh = MFMA(w1l[9], nh1, clh);
      f32x4 apre = (chh + chl) + (clh + b1r);
      f32x4 av = __builtin_elementwise_max(apre, vz);
      unsigned p0, p1, p2, p3;
      pack4(av.x, av.y, av.z, av.w, p0, p1, p2, p3);
      if (q15 < 2) {
        *(uint2*)&a_s[aW]       = make_uint2(p0, p1);
        *(uint2*)&a_s[aW + 128] = make_uint2(p2, p3);
      }
    }
    __syncthreads();   // bar A: a_s, hobs_s ready

    // ---- P2 ----
    if (gA) {
      // pack x[t+1]
      pack_frag(xr0, xr1, xch[0], xcl[0]);
      pack_frag(xr2, xr3, xch[1], xcl[1]);
      // MLP1(t+1) ranks 0-3
      f32x4 ehh = vz, ehl = vz, elh = vz;
      ehh = MFMA(w1h[0], rbh[(ph+1)%5][0], ehh); ehh = MFMA(w1h[1], rbh[(ph+1)%5][1], ehh);
      ehl = MFMA(w1h[0], rbl[(ph+1)%5][0], ehl); ehl = MFMA(w1h[1], rbl[(ph+1)%5][1], ehl);
      elh = MFMA(w1l[0], rbh[(ph+1)%5][0], elh); elh = MFMA(w1l[1], rbh[(ph+1)%5][1], elh);
      ehh = MFMA(w1h[2], rbh[(ph+2)%5][0], ehh); ehh = MFMA(w1h[3], rbh[(ph+2)%5][1], ehh);
      ehl = MFMA(w1h[2], rbl[(ph+2)%5][0], ehl); ehl = MFMA(w1h[3], rbl[(ph+2)%5][1], ehl);
      elh = MFMA(w1l[2], rbh[(ph+2)%5][0], elh); elh = MFMA(w1l[3], rbh[(ph+2)%5][1], elh);
      ehh = MFMA(w1h[4], rbh[(ph+3)%5][0], ehh); ehh = MFMA(w1h[5], rbh[(ph+3)%5][1], ehh);
      ehl = MFMA(w1h[4], rbl[(ph+3)%5][0], ehl); ehl = MFMA(w1h[5], rbl[(ph+3)%5][1], ehl);
      elh = MFMA(w1l[4], rbh[(ph+3)%5][0], elh); elh = MFMA(w1l[5], rbh[(ph+3)%5][1], elh);
      ehh = MFMA(w1h[6], rbh[(ph+4)%5][0], ehh); ehh = MFMA(w1h[7], rbh[(ph+4)%5][1], ehh);
      ehl = MFMA(w1h[6], rbl[(ph+4)%5][0], ehl); ehl = MFMA(w1h[7], rbl[(ph+4)%5][1], ehl);
      elh = MFMA(w1l[6], rbh[(ph+4)%5][0], elh); elh = MFMA(w1l[7], rbh[(ph+4)%5][1], elh);
      chh = ehh; chl = ehl; clh = elh;
    } else {
      // MLP2 on a_s
      bf16x8 ah0 = *(const bf16x8*)&a_s[aRb +   0];
      bf16x8 ah1 = *(const bf16x8*)&a_s[aRb +  32];
      bf16x8 ah2 = *(const bf16x8*)&a_s[aRb +  64];
      bf16x8 ah3 = *(const bf16x8*)&a_s[aRb +  96];
      bf16x8 al0 = *(const bf16x8*)&a_s[aRb + 128];
      bf16x8 al1 = *(const bf16x8*)&a_s[aRb + 160];
      bf16x8 al2 = *(const bf16x8*)&a_s[aRb + 192];
      bf16x8 al3 = *(const bf16x8*)&a_s[aRb + 224];
      // MLP1(t+1) ranks 0,1 (register ring) overlap the a_s latency
      f32x4 ghh = vz, ghl = vz, glh = vz;
      ghh = MFMA(w1h[0], rbh[(ph+1)%5][0], ghh); ghh = MFMA(w1h[1], rbh[(ph+1)%5][1], ghh);
      ghl = MFMA(w1h[0], rbl[(ph+1)%5][0], ghl); ghl = MFMA(w1h[1], rbl[(ph+1)%5][1], ghl);
      glh = MFMA(w1l[0], rbh[(ph+1)%5][0], glh); glh = MFMA(w1l[1], rbh[(ph+1)%5][1], glh);
      ghh = MFMA(w1h[2], rbh[(ph+2)%5][0], ghh); ghh = MFMA(w1h[3], rbh[(ph+2)%5][1], ghh);
      ghl = MFMA(w1h[2], rbl[(ph+2)%5][0], ghl); ghl = MFMA(w1h[3], rbl[(ph+2)%5][1], ghl);
      glh = MFMA(w1l[2], rbh[(ph+2)%5][0], glh); glh = MFMA(w1l[3], rbh[(ph+2)%5][1], glh);
      f32x4 mhh = b2r, mhl = vz, mlh = vz;
      mhh = MFMA(wxh[0], ah0, mhh); mhl = MFMA(wxh[0], al0, mhl); mlh = MFMA(wxl[0], ah0, mlh);
      mhh = MFMA(wxh[1], ah1, mhh); mhl = MFMA(wxh[1], al1, mhl); mlh = MFMA(wxl[1], ah1, mlh);
      mhh = MFMA(wxh[2], ah2, mhh); mhl = MFMA(wxh[2], al2, mhl); mlh = MFMA(wxl[2], ah2, mlh);
      mhh = MFMA(wxh[3], ah3, mhh); mhl = MFMA(wxh[3], al3, mhl); mlh = MFMA(wxl[3], ah3, mlh);
      chh = ghh; chl = ghl; clh = glh;
      f32x4 hm = (mhh + mhl) + mlh;
      f32x4 hobs = *(const f32x4*)&hobs_s[c01*64 + r0c];
      f32x4 hn = (t >= KEEP) ? (hobs + hm) * 0.5f : hobs;
      if (q15 < 2) {
        *(f32x4*)(io + (size_t)t*BATCH*HID + (size_t)(b0 + q15)*HID + r0c) = hn;
        if (t == TSTEPS-1)
          *(f32x4*)(io + (size_t)TSTEPS*BATCH*HID + (size_t)(b0 + q15)*HID + r0c) = hn;
        *(f32x4*)&h_s[q15*64 + r0c] = hn;
        unsigned n0, n1, n2, n3;
        pack4(hn.x, hn.y, hn.z, hn.w, n0, n1, n2, n3);
        *(uint2*)&B1lds[bWH]       = make_uint2(n0, n1);
        *(uint2*)&B1lds[bWH + 512] = make_uint2(n2, n3);
      }
    }
    __syncthreads();   // bar B: h_t staged
  };

  for (t5 = 0; t5 < TSTEPS; t5 += 5) {
    step(IC<0>{});
    step(IC<1>{});
    step(IC<2>{});
    step(IC<3>{});
    step(IC<4>{});
  }
}

extern "C" void kernel_launch(void* const* d_in, const int* in_sizes, int n_in,
                              void* d_out, int out_size, void* d_ws, size_t ws_size,
                              hipStream_t stream) {
  (void)in_sizes; (void)n_in; (void)out_size; (void)d_ws; (void)ws_size;
  const float* x    = (const float*)d_in[0];
  const float* h0   = (const float*)d_in[1];
  const float* W_in = (const float*)d_in[2];
  const float* b_in = (const float*)d_in[3];
  const float* W_hh = (const float*)d_in[4];
  const float* b_hh = (const float*)d_in[5];
  const float* W1   = (const float*)d_in[6];
  const float* b1   = (const float*)d_in[7];
  const float* W2   = (const float*)d_in[8];
  const float* b2   = (const float*)d_in[9];
  float* out = (float*)d_out;

  seq_kernel<<<NBLK, NTHR, 0, stream>>>(x, out, h0, W_in, b_in, W_hh, b_hh, W1, b1, W2, b2);
}

// Round 6
// 1210.101 us; speedup vs baseline: 1.2906x; 1.2906x over previous
//
#include <hip/hip_runtime.h>

typedef short bf16x8 __attribute__((ext_vector_type(8)));
typedef float f32x4  __attribute__((ext_vector_type(4)));

#define TSTEPS 1000
#define BATCH  512
#define HID    64
#define INPD   64
#define FEAT   128
#define KEEP   5
#define KH     320
#define ALPHA  0.2f
#define BB     2
#define NBLK   (BATCH/BB)   // 256
#define NTHR   512

#define MFMA(a,b,c) __builtin_amdgcn_mfma_f32_16x16x32_bf16(a, b, c, 0, 0, 0)

template<int P> struct IC { static constexpr int v = P; };

// split 4 f32 into bf16-hi (truncated) and bf16-lo (rounded residual), packed 2-per-u32
__device__ __forceinline__ void pack4(float x0, float x1, float x2, float x3,
                                      unsigned &h0, unsigned &h1,
                                      unsigned &l0, unsigned &l1) {
  unsigned a0 = __float_as_uint(x0), a1 = __float_as_uint(x1);
  unsigned a2 = __float_as_uint(x2), a3 = __float_as_uint(x3);
  h0 = __builtin_amdgcn_perm(a1, a0, 0x07060302u);   // {bf16(x1), bf16(x0)}
  h1 = __builtin_amdgcn_perm(a3, a2, 0x07060302u);
  float r0 = x0 - __uint_as_float(a0 & 0xFFFF0000u);
  float r1 = x1 - __uint_as_float(a1 & 0xFFFF0000u);
  float r2 = x2 - __uint_as_float(a2 & 0xFFFF0000u);
  float r3 = x3 - __uint_as_float(a3 & 0xFFFF0000u);
  asm("v_cvt_pk_bf16_f32 %0, %1, %2" : "=v"(l0) : "v"(r0), "v"(r1));
  asm("v_cvt_pk_bf16_f32 %0, %1, %2" : "=v"(l1) : "v"(r2), "v"(r3));
}

__device__ __forceinline__ void pack_frag(float4 v0, float4 v1, bf16x8 &hi, bf16x8 &lo) {
  int4 h4, l4;
  pack4(v0.x, v0.y, v0.z, v0.w, (unsigned&)h4.x, (unsigned&)h4.y, (unsigned&)l4.x, (unsigned&)l4.y);
  pack4(v1.x, v1.y, v1.z, v1.w, (unsigned&)h4.z, (unsigned&)h4.w, (unsigned&)l4.z, (unsigned&)l4.w);
  hi = __builtin_bit_cast(bf16x8, h4);
  lo = __builtin_bit_cast(bf16x8, l4);
}

__device__ __forceinline__ void load_wfrag(const float* p, bf16x8 &hi, bf16x8 &lo) {
  float4 v0 = *(const float4*)p;
  float4 v1 = *(const float4*)(p + 4);
  pack_frag(v0, v1, hi, lo);
}

// ---------------- single persistent MFMA kernel, round-4 skeleton rebalanced ----------------
// 256 blocks (1/CU) x 8 waves, BB=2, 3 barriers/step, 42 MFMA per wave per step.
// P1 (all): MLP1 30 MFMA -> a_s         (w4-7 also issue x[t+1] raw loads at top)
// P2: w0-3: RNN 6 + MLP2-kt23 6 -> hobs,m2p (regs) | w4-7: MLP2-kt01 6 -> hm_s
// P3: w0-3: finalize h_t, io write, stage B1lds    | w4-7: pack x, XIN 6 -> xin_s
__global__ __launch_bounds__(NTHR, 2) void seq_kernel(
    const float* __restrict__ x,    float* __restrict__ io,
    const float* __restrict__ h0g,
    const float* __restrict__ W_in, const float* __restrict__ b_in,
    const float* __restrict__ W_hh, const float* __restrict__ b_hh,
    const float* __restrict__ W1,   const float* __restrict__ b1,
    const float* __restrict__ W2,   const float* __restrict__ b2) {

  __shared__ __align__(16) short B1lds[2048];   // newest-h frag staging
  __shared__ __align__(16) short a_s[544];      // relu(mlp1) bf16, col stride 264
  __shared__ __align__(16) float hm_s[128];     // mlp2 kt01 partial [col2][h64]
  __shared__ __align__(16) float xin_s[128];    // xin(t+1) incl biases [col2][h64]

  const int tid  = threadIdx.x;
  const int w    = tid >> 6;
  const int lane = tid & 63;
  const int q15  = lane & 15;
  const int g    = lane >> 4;
  const int b0   = blockIdx.x * BB;
  const bool gA  = (w < 4);
  const int r0c  = 16*(w & 3) + 4*g;   // 64-row base (RNN / MLP2 / h / xin)
  const int f0   = 16*w + 4*g;         // 128-row base (MLP1)
  const int c01  = q15 & 1;

  const int aW  = q15*264 + f0;        // a_s write (hi), +128 lo; q15<2 only
  const int aRb = c01*264 + 8*g;       // a_s read base (+kt*32, +128 lo)
  const int bWH = (r0c>>5)*1024 + ((r0c>>3)&3)*128 + q15*8 + (r0c&7);
  const int bRD = g*128 + q15*8;

  const f32x4 vz = {0.f, 0.f, 0.f, 0.f};

  // ---- weight fragments ----
  bf16x8 w1h[10], w1l[10];
#pragma unroll
  for (int jt = 0; jt < 10; ++jt)
    load_wfrag(W1 + (size_t)(16*w + q15)*KH + jt*32 + 8*g, w1h[jt], w1l[jt]);

  bf16x8 wxh[4], wxl[4];
  f32x4 biasv = vz, b2r = vz;
  f32x4 b1r = *(const f32x4*)(b1 + f0);
  if (gA) {
    // [0,1]=W_hh kt0,1 ; [2,3]=W2 rows 16w, kt2,3
#pragma unroll
    for (int kt = 0; kt < 2; ++kt) {
      load_wfrag(W_hh + (size_t)(16*w + q15)*HID  + kt*32 + 8*g,       wxh[kt],   wxl[kt]);
      load_wfrag(W2   + (size_t)(16*w + q15)*FEAT + (2+kt)*32 + 8*g,   wxh[2+kt], wxl[2+kt]);
    }
    b2r = *(const f32x4*)(b2 + r0c);
  } else {
    // [0,1]=W2 rows 16(w-4), kt0,1 ; [2,3]=W_in kt0,1
#pragma unroll
    for (int kt = 0; kt < 2; ++kt) {
      load_wfrag(W2   + (size_t)(16*(w-4) + q15)*FEAT + kt*32 + 8*g,   wxh[kt],   wxl[kt]);
      load_wfrag(W_in + (size_t)(16*(w-4) + q15)*INPD + kt*32 + 8*g,   wxh[2+kt], wxl[2+kt]);
    }
    biasv = *(const f32x4*)(b_in + r0c) + *(const f32x4*)(b_hh + r0c);
  }

  for (int i = tid; i < 1024; i += NTHR) ((unsigned*)B1lds)[i] = 0u;
  __syncthreads();

  // ---- state init ----
  f32x4 hprev = vz;
  if (gA) {
    if (q15 < 2) {
      hprev = *(const f32x4*)(h0g + (size_t)(b0 + q15)*HID + r0c);
      unsigned n0, n1, n2, n3;
      pack4(hprev.x, hprev.y, hprev.z, hprev.w, n0, n1, n2, n3);
      *(uint2*)&B1lds[bWH]       = make_uint2(n0, n1);
      *(uint2*)&B1lds[bWH + 512] = make_uint2(n2, n3);
    }
  } else {
    // xin for t=0
    const float* xp = x + (size_t)(b0 + c01)*INPD + 8*g;
    float4 v0 = *(const float4*)xp;        float4 v1 = *(const float4*)(xp + 4);
    float4 v2 = *(const float4*)(xp + 32); float4 v3 = *(const float4*)(xp + 36);
    bf16x8 th0, tl0, th1, tl1;
    pack_frag(v0, v1, th0, tl0);
    pack_frag(v2, v3, th1, tl1);
    f32x4 dhh = biasv, dhl = vz, dlh = vz;
    dhh = MFMA(wxh[2], th0, dhh); dhh = MFMA(wxh[3], th1, dhh);
    dhl = MFMA(wxh[2], tl0, dhl); dhl = MFMA(wxh[3], tl1, dhl);
    dlh = MFMA(wxl[2], th0, dlh); dlh = MFMA(wxl[3], th1, dlh);
    f32x4 xi = (dhh + dhl) + dlh;
    if (q15 < 2) *(f32x4*)&xin_s[q15*64 + r0c] = xi;
  }

  bf16x8 rbh[KEEP][2], rbl[KEEP][2];
  const bf16x8 z8 = {0,0,0,0,0,0,0,0};
#pragma unroll
  for (int s = 0; s < KEEP; ++s) {
    rbh[s][0] = z8; rbl[s][0] = z8; rbh[s][1] = z8; rbl[s][1] = z8;
  }
  __syncthreads();

  int t5 = 0;
  auto step = [&](auto pc) {
    constexpr int ph = decltype(pc)::v;
    constexpr int sN = (ph + 4) % 5;           // slot of h_{t-1}
    const int t = t5 + ph;

    // ---- P1 ----
    float4 xr0, xr1, xr2, xr3;                 // w4-7: raw x[t+1], consumed in P3
    if (!gA) {
      const int tn = (t + 1 < TSTEPS) ? t + 1 : t;
      const float* xp = x + (size_t)tn*BATCH*INPD + (size_t)(b0 + c01)*INPD + 8*g;
      xr0 = *(const float4*)xp;        xr1 = *(const float4*)(xp + 4);
      xr2 = *(const float4*)(xp + 32); xr3 = *(const float4*)(xp + 36);
    }

    rbh[sN][0] = *(const bf16x8*)&B1lds[bRD];
    rbl[sN][0] = *(const bf16x8*)&B1lds[bRD + 512];
    rbh[sN][1] = *(const bf16x8*)&B1lds[bRD + 1024];
    rbl[sN][1] = *(const bf16x8*)&B1lds[bRD + 1536];

    // MLP1: K=320, 5 slots x 2 ktiles, 3-product split; newest slot last
    f32x4 chh = vz, chl = vz, clh = vz;
#pragma unroll
    for (int e = 1; e <= 5; ++e) {
      const int s = (sN + e) % 5;
      const int r = ((s - ph) % 5 + 5) % 5;
#pragma unroll
      for (int q = 0; q < 2; ++q) {
        const int jt = 2*r + q;
        chh = MFMA(w1h[jt], rbh[s][q], chh);
        chl = MFMA(w1h[jt], rbl[s][q], chl);
        clh = MFMA(w1l[jt], rbh[s][q], clh);
      }
    }
    {
      f32x4 apre = (chh + chl) + (clh + b1r);
      f32x4 av = __builtin_elementwise_max(apre, vz);
      unsigned p0, p1, p2, p3;
      pack4(av.x, av.y, av.z, av.w, p0, p1, p2, p3);
      if (q15 < 2) {
        *(uint2*)&a_s[aW]       = make_uint2(p0, p1);
        *(uint2*)&a_s[aW + 128] = make_uint2(p2, p3);
      }
    }
    __syncthreads();   // bar A: a_s ready

    // ---- P2 ----
    f32x4 hobs = vz, m2p = vz;
    if (gA) {
      bf16x8 ah2 = *(const bf16x8*)&a_s[aRb +  64];
      bf16x8 ah3 = *(const bf16x8*)&a_s[aRb +  96];
      bf16x8 al2 = *(const bf16x8*)&a_s[aRb + 192];
      bf16x8 al3 = *(const bf16x8*)&a_s[aRb + 224];
      f32x4 xinv = vz;
      if (q15 < 2) xinv = *(const f32x4*)&xin_s[q15*64 + r0c];
      // RNN on newest frag (register operands, overlap a_s latency)
      f32x4 dhh = vz, dhl = vz, dlh = vz;
      dhh = MFMA(wxh[0], rbh[sN][0], dhh); dhh = MFMA(wxh[1], rbh[sN][1], dhh);
      dhl = MFMA(wxh[0], rbl[sN][0], dhl); dhl = MFMA(wxh[1], rbl[sN][1], dhl);
      dlh = MFMA(wxl[0], rbh[sN][0], dlh); dlh = MFMA(wxl[1], rbh[sN][1], dlh);
      // MLP2 kt2,3 partial (stays in registers)
      f32x4 mhh = vz, mhl = vz, mlh = vz;
      mhh = MFMA(wxh[2], ah2, mhh); mhh = MFMA(wxh[3], ah3, mhh);
      mhl = MFMA(wxh[2], al2, mhl); mhl = MFMA(wxh[3], al3, mhl);
      mlh = MFMA(wxl[2], ah2, mlh); mlh = MFMA(wxl[3], ah3, mlh);
      m2p = (mhh + mhl) + mlh;
      f32x4 pre = (dhh + dhl) + dlh + xinv;    // xin includes biases
      f32x4 rl = __builtin_elementwise_max(pre, vz);
      hobs = hprev * (1.f - ALPHA) + rl * ALPHA;
    } else {
      bf16x8 ah0 = *(const bf16x8*)&a_s[aRb +   0];
      bf16x8 ah1 = *(const bf16x8*)&a_s[aRb +  32];
      bf16x8 al0 = *(const bf16x8*)&a_s[aRb + 128];
      bf16x8 al1 = *(const bf16x8*)&a_s[aRb + 160];
      f32x4 mhh = vz, mhl = vz, mlh = vz;
      mhh = MFMA(wxh[0], ah0, mhh); mhh = MFMA(wxh[1], ah1, mhh);
      mhl = MFMA(wxh[0], al0, mhl); mhl = MFMA(wxh[1], al1, mhl);
      mlh = MFMA(wxl[0], ah0, mlh); mlh = MFMA(wxl[1], ah1, mlh);
      f32x4 hmv = (mhh + mhl) + mlh;
      if (q15 < 2) *(f32x4*)&hm_s[q15*64 + r0c] = hmv;
    }
    __syncthreads();   // bar B: hm_s ready

    // ---- P3 ----
    if (gA) {
      f32x4 hmo = vz;
      if (q15 < 2) hmo = *(const f32x4*)&hm_s[q15*64 + r0c];
      f32x4 hm = hmo + m2p + b2r;
      f32x4 hn = (t >= KEEP) ? (hobs + hm) * 0.5f : hobs;
      if (q15 < 2) {
        *(f32x4*)(io + (size_t)t*BATCH*HID + (size_t)(b0 + q15)*HID + r0c) = hn;
        if (t == TSTEPS-1)
          *(f32x4*)(io + (size_t)TSTEPS*BATCH*HID + (size_t)(b0 + q15)*HID + r0c) = hn;
        unsigned n0, n1, n2, n3;
        pack4(hn.x, hn.y, hn.z, hn.w, n0, n1, n2, n3);
        *(uint2*)&B1lds[bWH]       = make_uint2(n0, n1);
        *(uint2*)&B1lds[bWH + 512] = make_uint2(n2, n3);
      }
      hprev = hn;
    } else {
      bf16x8 th0, tl0, th1, tl1;
      pack_frag(xr0, xr1, th0, tl0);
      pack_frag(xr2, xr3, th1, tl1);
      f32x4 dhh = biasv, dhl = vz, dlh = vz;
      dhh = MFMA(wxh[2], th0, dhh); dhh = MFMA(wxh[3], th1, dhh);
      dhl = MFMA(wxh[2], tl0, dhl); dhl = MFMA(wxh[3], tl1, dhl);
      dlh = MFMA(wxl[2], th0, dlh); dlh = MFMA(wxl[3], th1, dlh);
      f32x4 xi = (dhh + dhl) + dlh;
      if (q15 < 2) *(f32x4*)&xin_s[q15*64 + r0c] = xi;
    }
    __syncthreads();   // bar C: B1lds + xin_s staged
  };

  for (t5 = 0; t5 < TSTEPS; t5 += 5) {
    step(IC<0>{});
    step(IC<1>{});
    step(IC<2>{});
    step(IC<3>{});
    step(IC<4>{});
  }
}

extern "C" void kernel_launch(void* const* d_in, const int* in_sizes, int n_in,
                              void* d_out, int out_size, void* d_ws, size_t ws_size,
                              hipStream_t stream) {
  (void)in_sizes; (void)n_in; (void)out_size; (void)d_ws; (void)ws_size;
  const float* x    = (const float*)d_in[0];
  const float* h0   = (const float*)d_in[1];
  const float* W_in = (const float*)d_in[2];
  const float* b_in = (const float*)d_in[3];
  const float* W_hh = (const float*)d_in[4];
  const float* b_hh = (const float*)d_in[5];
  const float* W1   = (const float*)d_in[6];
  const float* b1   = (const float*)d_in[7];
  const float* W2   = (const float*)d_in[8];
  const float* b2   = (const float*)d_in[9];
  float* out = (float*)d_out;

  seq_kernel<<<NBLK, NTHR, 0, stream>>>(x, out, h0, W_in, b_in, W_hh, b_hh, W1, b1, W2, b2);
}